// Round 1
// baseline (5827.838 us; speedup 1.0000x reference)
//
#include <hip/hip_runtime.h>

#define N_NODES 100000
#define N_EDGES 1600000
#define NFEAT 256
#define NHID 128
#define NCLS 10

// out[n][j] = sum_k act(in[n][k]) * W[k][j]
// act(v) = relu(v + bias[k]) when bias != nullptr, else v.
// Thread layout: 256 thr/block; j0 = (tid&31)*4 covers 128 features; each
// 32-thread group owns 4 consecutive nodes -> 32 nodes/block.
template<int K>
__global__ void gemm_act(const float* __restrict__ in, const float* __restrict__ W,
                         const float* __restrict__ bias, float* __restrict__ out,
                         int n_nodes) {
  int tid = blockIdx.x * 256 + threadIdx.x;
  int j0 = (threadIdx.x & 31) * 4;
  int n0 = (tid >> 5) * 4;
  if (n0 >= n_nodes) return;

  float4 acc0 = {0,0,0,0}, acc1 = {0,0,0,0}, acc2 = {0,0,0,0}, acc3 = {0,0,0,0};

  for (int k0 = 0; k0 < K; k0 += 4) {
    float4 xa0 = *(const float4*)&in[(long long)(n0+0)*K + k0];
    float4 xa1 = *(const float4*)&in[(long long)(n0+1)*K + k0];
    float4 xa2 = *(const float4*)&in[(long long)(n0+2)*K + k0];
    float4 xa3 = *(const float4*)&in[(long long)(n0+3)*K + k0];
    if (bias) {
      float4 b4 = *(const float4*)&bias[k0];
      xa0.x = fmaxf(xa0.x + b4.x, 0.f); xa0.y = fmaxf(xa0.y + b4.y, 0.f);
      xa0.z = fmaxf(xa0.z + b4.z, 0.f); xa0.w = fmaxf(xa0.w + b4.w, 0.f);
      xa1.x = fmaxf(xa1.x + b4.x, 0.f); xa1.y = fmaxf(xa1.y + b4.y, 0.f);
      xa1.z = fmaxf(xa1.z + b4.z, 0.f); xa1.w = fmaxf(xa1.w + b4.w, 0.f);
      xa2.x = fmaxf(xa2.x + b4.x, 0.f); xa2.y = fmaxf(xa2.y + b4.y, 0.f);
      xa2.z = fmaxf(xa2.z + b4.z, 0.f); xa2.w = fmaxf(xa2.w + b4.w, 0.f);
      xa3.x = fmaxf(xa3.x + b4.x, 0.f); xa3.y = fmaxf(xa3.y + b4.y, 0.f);
      xa3.z = fmaxf(xa3.z + b4.z, 0.f); xa3.w = fmaxf(xa3.w + b4.w, 0.f);
    }
    float4 w0 = *(const float4*)&W[(k0+0)*NHID + j0];
    float4 w1 = *(const float4*)&W[(k0+1)*NHID + j0];
    float4 w2 = *(const float4*)&W[(k0+2)*NHID + j0];
    float4 w3 = *(const float4*)&W[(k0+3)*NHID + j0];

#define FMA4(ACC, XA) \
    ACC.x += XA.x*w0.x + XA.y*w1.x + XA.z*w2.x + XA.w*w3.x; \
    ACC.y += XA.x*w0.y + XA.y*w1.y + XA.z*w2.y + XA.w*w3.y; \
    ACC.z += XA.x*w0.z + XA.y*w1.z + XA.z*w2.z + XA.w*w3.z; \
    ACC.w += XA.x*w0.w + XA.y*w1.w + XA.z*w2.w + XA.w*w3.w;
    FMA4(acc0, xa0) FMA4(acc1, xa1) FMA4(acc2, xa2) FMA4(acc3, xa3)
#undef FMA4
  }
  *(float4*)&out[(long long)(n0+0)*NHID + j0] = acc0;
  *(float4*)&out[(long long)(n0+1)*NHID + j0] = acc1;
  *(float4*)&out[(long long)(n0+2)*NHID + j0] = acc2;
  *(float4*)&out[(long long)(n0+3)*NHID + j0] = acc3;
}

// For each edge e: agg[dst[e]][:] += support[src[e]][:] * w[e]
// 32 threads per edge, 4 features each (float4 gather, 4 scalar atomics).
__global__ void scatter_edges(const float* __restrict__ sup, const int* __restrict__ src,
                              const int* __restrict__ dst, const float* __restrict__ ew,
                              float* __restrict__ agg) {
  long long tid = (long long)blockIdx.x * 256 + threadIdx.x;
  int e = (int)(tid >> 5);
  if (e >= N_EDGES) return;
  int lane = (int)(tid & 31);
  int s = src[e], d = dst[e];
  float w = ew[e];
  float4 v = *(const float4*)&sup[(long long)s * NHID + lane * 4];
  float* ap = &agg[(long long)d * NHID + lane * 4];
  atomicAdd(ap + 0, v.x * w);
  atomicAdd(ap + 1, v.y * w);
  atomicAdd(ap + 2, v.z * w);
  atomicAdd(ap + 3, v.w * w);
}

// c[src[e]] += ew[e]
__global__ void src_weight_hist(const int* __restrict__ src, const float* __restrict__ ew,
                                float* __restrict__ c) {
  int e = blockIdx.x * 256 + threadIdx.x;
  if (e < N_EDGES) atomicAdd(&c[src[e]], ew[e]);
}

// s2[j] = sum_n c[n] * relu(agg2[n][j] + b2[j])
__global__ void weighted_colsum(const float* __restrict__ agg2, const float* __restrict__ b2,
                                const float* __restrict__ c, float* __restrict__ s2) {
  int j = threadIdx.x & 127;
  int half = threadIdx.x >> 7;
  float bj = b2[j];
  float acc = 0.f;
  for (int n = blockIdx.x * 2 + half; n < N_NODES; n += gridDim.x * 2) {
    float v = fmaxf(agg2[(long long)n * NHID + j] + bj, 0.f);
    acc += v * c[n];
  }
  __shared__ float red[128];
  if (half) red[j] = acc;
  __syncthreads();
  if (!half) atomicAdd(&s2[j], acc + red[j]);
}

// g = (s2/N) @ W3 + b3 ; out = g @ lin_w + lin_b
__global__ void head(const float* __restrict__ s2, const float* __restrict__ W3,
                     const float* __restrict__ b3, const float* __restrict__ lw,
                     const float* __restrict__ lb, float* __restrict__ out) {
  __shared__ float s2s[128], g[128];
  int j = threadIdx.x;
  s2s[j] = s2[j] * (1.0f / N_NODES);
  __syncthreads();
  float acc = b3[j];
  for (int k = 0; k < 128; k++) acc += s2s[k] * W3[k * NHID + j];
  g[j] = acc;
  __syncthreads();
  if (j < NCLS) {
    float o = lb[j];
    for (int k = 0; k < 128; k++) o += g[k] * lw[k * NCLS + j];
    out[j] = o;
  }
}

extern "C" void kernel_launch(void* const* d_in, const int* in_sizes, int n_in,
                              void* d_out, int out_size, void* d_ws, size_t ws_size,
                              hipStream_t stream) {
  const float* x  = (const float*)d_in[0];
  const int*   ei = (const int*)d_in[1];
  const float* ew = (const float*)d_in[2];
  const float* W1 = (const float*)d_in[3];
  const float* b1 = (const float*)d_in[4];
  const float* W2 = (const float*)d_in[5];
  const float* b2 = (const float*)d_in[6];
  const float* W3 = (const float*)d_in[7];
  const float* b3 = (const float*)d_in[8];
  const float* lw = (const float*)d_in[9];
  const float* lb = (const float*)d_in[10];
  const int* src = ei;
  const int* dst = ei + N_EDGES;

  char* ws = (char*)d_ws;
  const size_t SUP_BYTES = (size_t)N_NODES * NHID * sizeof(float); // 51.2 MB
  float* sup = (float*)ws;
  float* agg = (float*)(ws + SUP_BYTES);
  float* c   = (float*)(ws + 2 * SUP_BYTES);
  float* s2  = (float*)(ws + 2 * SUP_BYTES + 400000);

  // ---- layer 1: support = x @ W1 ; agg = scatter(support) ----
  gemm_act<NFEAT><<<3125, 256, 0, stream>>>(x, W1, nullptr, sup, N_NODES);
  hipMemsetAsync(agg, 0, SUP_BYTES, stream);
  scatter_edges<<<200000, 256, 0, stream>>>(sup, src, dst, ew, agg);

  // ---- layer 2: support2 = relu(agg + b1) @ W2 ; agg2 = scatter(support2) ----
  gemm_act<NHID><<<3125, 256, 0, stream>>>(agg, W2, b1, sup, N_NODES);
  hipMemsetAsync(agg, 0, SUP_BYTES, stream);
  scatter_edges<<<200000, 256, 0, stream>>>(sup, src, dst, ew, agg);

  // ---- layer 3 (algebraically reduced) + pool + head ----
  hipMemsetAsync(c, 0, N_NODES * sizeof(float), stream);
  hipMemsetAsync(s2, 0, 512, stream);
  src_weight_hist<<<6250, 256, 0, stream>>>(src, ew, c);
  weighted_colsum<<<256, 256, 0, stream>>>(agg, b2, c, s2);
  head<<<1, 128, 0, stream>>>(s2, W3, b3, lw, lb, (float*)d_out);
}

// Round 2
// 1011.928 us; speedup vs baseline: 5.7591x; 5.7591x over previous
//
#include <hip/hip_runtime.h>

#define N_NODES 100000
#define N_EDGES 1600000
#define NFEAT 256
#define NHID 128
#define NCLS 10

// ---------------- dense GEMM: out[n][j] = sum_k act(in[n][k]) * W[k][j] ----
// act(v) = relu(v + bias[k]) when bias != nullptr, else identity.
template<int K>
__global__ void gemm_act(const float* __restrict__ in, const float* __restrict__ W,
                         const float* __restrict__ bias, float* __restrict__ out,
                         int n_nodes) {
  int tid = blockIdx.x * 256 + threadIdx.x;
  int j0 = (threadIdx.x & 31) * 4;
  int n0 = (tid >> 5) * 4;
  if (n0 >= n_nodes) return;

  float4 acc0 = {0,0,0,0}, acc1 = {0,0,0,0}, acc2 = {0,0,0,0}, acc3 = {0,0,0,0};

  for (int k0 = 0; k0 < K; k0 += 4) {
    float4 xa0 = *(const float4*)&in[(long long)(n0+0)*K + k0];
    float4 xa1 = *(const float4*)&in[(long long)(n0+1)*K + k0];
    float4 xa2 = *(const float4*)&in[(long long)(n0+2)*K + k0];
    float4 xa3 = *(const float4*)&in[(long long)(n0+3)*K + k0];
    if (bias) {
      float4 b4 = *(const float4*)&bias[k0];
      xa0.x = fmaxf(xa0.x + b4.x, 0.f); xa0.y = fmaxf(xa0.y + b4.y, 0.f);
      xa0.z = fmaxf(xa0.z + b4.z, 0.f); xa0.w = fmaxf(xa0.w + b4.w, 0.f);
      xa1.x = fmaxf(xa1.x + b4.x, 0.f); xa1.y = fmaxf(xa1.y + b4.y, 0.f);
      xa1.z = fmaxf(xa1.z + b4.z, 0.f); xa1.w = fmaxf(xa1.w + b4.w, 0.f);
      xa2.x = fmaxf(xa2.x + b4.x, 0.f); xa2.y = fmaxf(xa2.y + b4.y, 0.f);
      xa2.z = fmaxf(xa2.z + b4.z, 0.f); xa2.w = fmaxf(xa2.w + b4.w, 0.f);
      xa3.x = fmaxf(xa3.x + b4.x, 0.f); xa3.y = fmaxf(xa3.y + b4.y, 0.f);
      xa3.z = fmaxf(xa3.z + b4.z, 0.f); xa3.w = fmaxf(xa3.w + b4.w, 0.f);
    }
    float4 w0 = *(const float4*)&W[(k0+0)*NHID + j0];
    float4 w1 = *(const float4*)&W[(k0+1)*NHID + j0];
    float4 w2 = *(const float4*)&W[(k0+2)*NHID + j0];
    float4 w3 = *(const float4*)&W[(k0+3)*NHID + j0];

#define FMA4(ACC, XA) \
    ACC.x += XA.x*w0.x + XA.y*w1.x + XA.z*w2.x + XA.w*w3.x; \
    ACC.y += XA.x*w0.y + XA.y*w1.y + XA.z*w2.y + XA.w*w3.y; \
    ACC.z += XA.x*w0.z + XA.y*w1.z + XA.z*w2.z + XA.w*w3.z; \
    ACC.w += XA.x*w0.w + XA.y*w1.w + XA.z*w2.w + XA.w*w3.w;
    FMA4(acc0, xa0) FMA4(acc1, xa1) FMA4(acc2, xa2) FMA4(acc3, xa3)
#undef FMA4
  }
  *(float4*)&out[(long long)(n0+0)*NHID + j0] = acc0;
  *(float4*)&out[(long long)(n0+1)*NHID + j0] = acc1;
  *(float4*)&out[(long long)(n0+2)*NHID + j0] = acc2;
  *(float4*)&out[(long long)(n0+3)*NHID + j0] = acc3;
}

// ---------------- CSR build ----------------
// deg[dst[e]]++ and c[src[e]] += w[e] in one pass.
__global__ void edge_prep(const int* __restrict__ src, const int* __restrict__ dst,
                          const float* __restrict__ ew, int* __restrict__ deg,
                          float* __restrict__ c) {
  int e = blockIdx.x * 256 + threadIdx.x;
  if (e >= N_EDGES) return;
  atomicAdd(&deg[dst[e]], 1);
  atomicAdd(&c[src[e]], ew[e]);
}

// block-level inclusive scan -> per-element exclusive-within-block + block sums
__global__ void scan1(const int* __restrict__ deg, int* __restrict__ ex,
                      int* __restrict__ bsum) {
  __shared__ int tmp[512];
  int i = blockIdx.x * 512 + threadIdx.x;
  int v = (i < N_NODES) ? deg[i] : 0;
  tmp[threadIdx.x] = v;
  __syncthreads();
  for (int off = 1; off < 512; off <<= 1) {
    int t = (threadIdx.x >= (unsigned)off) ? tmp[threadIdx.x - off] : 0;
    __syncthreads();
    tmp[threadIdx.x] += t;
    __syncthreads();
  }
  if (i < N_NODES) ex[i] = tmp[threadIdx.x] - v;   // exclusive within block
  if (threadIdx.x == 511) bsum[blockIdx.x] = tmp[511];
}

// single block: exclusive scan of the block sums (NB <= 256)
__global__ void scan2(int* __restrict__ bsum, int nb) {
  __shared__ int tmp[256];
  int v = (threadIdx.x < nb) ? bsum[threadIdx.x] : 0;
  tmp[threadIdx.x] = v;
  __syncthreads();
  for (int off = 1; off < 256; off <<= 1) {
    int t = (threadIdx.x >= (unsigned)off) ? tmp[threadIdx.x - off] : 0;
    __syncthreads();
    tmp[threadIdx.x] += t;
    __syncthreads();
  }
  if (threadIdx.x < nb) bsum[threadIdx.x] = tmp[threadIdx.x] - v;  // exclusive
}

// rowptr[i] = ex[i] + bsum[block]; cursor[i] = rowptr[i]; rowptr[N]=E
__global__ void scan3(int* __restrict__ rowptr, const int* __restrict__ bsum,
                      int* __restrict__ cursor) {
  int i = blockIdx.x * 512 + threadIdx.x;
  if (i < N_NODES) {
    int r = rowptr[i] + bsum[blockIdx.x];
    rowptr[i] = r;
    cursor[i] = r;
  }
  if (i == 0) rowptr[N_NODES] = N_EDGES;
}

// bucket-fill: sorted[pos] = (src, bits(w)) for each edge, bucketed by dst
__global__ void fill_csr(const int* __restrict__ src, const int* __restrict__ dst,
                         const float* __restrict__ ew, int* __restrict__ cursor,
                         int2* __restrict__ sorted) {
  int e = blockIdx.x * 256 + threadIdx.x;
  if (e >= N_EDGES) return;
  int d = dst[e];
  int pos = atomicAdd(&cursor[d], 1);
  sorted[pos] = make_int2(src[e], __float_as_int(ew[e]));
}

// ---------------- gather-only aggregation ----------------
// agg[n][:] = sum_{e in bucket(n)} sup[src_e][:] * w_e
// one 64-lane group per node, 2 floats per lane.
__global__ void aggregate(const float* __restrict__ sup, const int* __restrict__ rowptr,
                          const int2* __restrict__ sw, float* __restrict__ agg) {
  int node = blockIdx.x * 4 + (threadIdx.x >> 6);
  if (node >= N_NODES) return;
  int lane = threadIdx.x & 63;
  int beg = rowptr[node], end = rowptr[node + 1];
  float ax = 0.f, ay = 0.f;
  for (int i = beg; i < end; i++) {
    int2 m = sw[i];
    float w = __int_as_float(m.y);
    float2 v = *(const float2*)&sup[m.x * NHID + lane * 2];
    ax += v.x * w;
    ay += v.y * w;
  }
  float2* o = (float2*)&agg[node * NHID + lane * 2];
  *o = make_float2(ax, ay);
}

// layer-2 aggregate fused with weighted colsum:
// s2[j] += sum_n c[n] * relu(agg2[n][j] + b2[j]), agg2 never materialized.
__global__ void aggregate_colsum(const float* __restrict__ sup, const int* __restrict__ rowptr,
                                 const int2* __restrict__ sw, const float* __restrict__ b2,
                                 const float* __restrict__ c, float* __restrict__ s2) {
  int grp = threadIdx.x >> 6;
  int lane = threadIdx.x & 63;
  float2 b = *(const float2*)&b2[lane * 2];
  float csx = 0.f, csy = 0.f;
  for (int node = blockIdx.x * 4 + grp; node < N_NODES; node += gridDim.x * 4) {
    int beg = rowptr[node], end = rowptr[node + 1];
    float ax = 0.f, ay = 0.f;
    for (int i = beg; i < end; i++) {
      int2 m = sw[i];
      float w = __int_as_float(m.y);
      float2 v = *(const float2*)&sup[m.x * NHID + lane * 2];
      ax += v.x * w;
      ay += v.y * w;
    }
    float cn = c[node];
    csx += fmaxf(ax + b.x, 0.f) * cn;
    csy += fmaxf(ay + b.y, 0.f) * cn;
  }
  __shared__ float red[4][128];
  red[grp][lane * 2] = csx;
  red[grp][lane * 2 + 1] = csy;
  __syncthreads();
  if (grp == 0) {
    float s0 = red[0][lane*2] + red[1][lane*2] + red[2][lane*2] + red[3][lane*2];
    float s1 = red[0][lane*2+1] + red[1][lane*2+1] + red[2][lane*2+1] + red[3][lane*2+1];
    atomicAdd(&s2[lane * 2], s0);
    atomicAdd(&s2[lane * 2 + 1], s1);
  }
}

// ---------------- head: g = (s2/N) @ W3 + b3 ; out = g @ lin_w + lin_b ----
__global__ void head(const float* __restrict__ s2, const float* __restrict__ W3,
                     const float* __restrict__ b3, const float* __restrict__ lw,
                     const float* __restrict__ lb, float* __restrict__ out) {
  __shared__ float s2s[128], g[128];
  int j = threadIdx.x;
  s2s[j] = s2[j] * (1.0f / N_NODES);
  __syncthreads();
  float acc = b3[j];
  for (int k = 0; k < 128; k++) acc += s2s[k] * W3[k * NHID + j];
  g[j] = acc;
  __syncthreads();
  if (j < NCLS) {
    float o = lb[j];
    for (int k = 0; k < 128; k++) o += g[k] * lw[k * NCLS + j];
    out[j] = o;
  }
}

extern "C" void kernel_launch(void* const* d_in, const int* in_sizes, int n_in,
                              void* d_out, int out_size, void* d_ws, size_t ws_size,
                              hipStream_t stream) {
  const float* x  = (const float*)d_in[0];
  const int*   ei = (const int*)d_in[1];
  const float* ew = (const float*)d_in[2];
  const float* W1 = (const float*)d_in[3];
  const float* b1 = (const float*)d_in[4];
  const float* W2 = (const float*)d_in[5];
  const float* b2 = (const float*)d_in[6];
  const float* W3 = (const float*)d_in[7];
  const float* b3 = (const float*)d_in[8];
  const float* lw = (const float*)d_in[9];
  const float* lb = (const float*)d_in[10];
  const int* src = ei;
  const int* dst = ei + N_EDGES;

  char* ws = (char*)d_ws;
  const size_t SUP_BYTES = (size_t)N_NODES * NHID * sizeof(float);   // 51.2 MB
  const size_t NODE_I    = ((size_t)(N_NODES + 1) * 4 + 511) & ~511ull;
  size_t off = 0;
  float* sup    = (float*)(ws + off); off += SUP_BYTES;
  float* agg    = (float*)(ws + off); off += SUP_BYTES;
  int*   deg    = (int*)  (ws + off); off += NODE_I;
  int*   rowptr = (int*)  (ws + off); off += NODE_I;
  int*   cursor = (int*)  (ws + off); off += NODE_I;
  float* c      = (float*)(ws + off); off += NODE_I;
  float* s2     = (float*)(ws + off); off += 512;
  int*   bsum   = (int*)  (ws + off); off += 1024;
  int2*  sorted = (int2*) (ws + off); off += (size_t)N_EDGES * 8;    // 12.8 MB

  const int NB = (N_NODES + 511) / 512;   // 196 scan blocks

  // zero the small accumulators
  hipMemsetAsync(deg, 0, N_NODES * sizeof(int), stream);
  hipMemsetAsync(c, 0, N_NODES * sizeof(float), stream);
  hipMemsetAsync(s2, 0, 512, stream);

  // ---- CSR build (per call; deterministic work) ----
  edge_prep<<<(N_EDGES + 255) / 256, 256, 0, stream>>>(src, dst, ew, deg, c);
  scan1<<<NB, 512, 0, stream>>>(deg, rowptr, bsum);
  scan2<<<1, 256, 0, stream>>>(bsum, NB);
  scan3<<<NB, 512, 0, stream>>>(rowptr, bsum, cursor);
  fill_csr<<<(N_EDGES + 255) / 256, 256, 0, stream>>>(src, dst, ew, cursor, sorted);

  // ---- layer 1: sup = x @ W1 ; agg = A @ sup ----
  gemm_act<NFEAT><<<3125, 256, 0, stream>>>(x, W1, nullptr, sup, N_NODES);
  aggregate<<<25000, 256, 0, stream>>>(sup, rowptr, sorted, agg);

  // ---- layer 2: sup = relu(agg + b1) @ W2 ; s2 = c^T relu(A sup + b2) ----
  gemm_act<NHID><<<3125, 256, 0, stream>>>(agg, W2, b1, sup, N_NODES);
  aggregate_colsum<<<3125, 256, 0, stream>>>(sup, rowptr, sorted, b2, c, s2);

  // ---- head ----
  head<<<1, 128, 0, stream>>>(s2, W3, b3, lw, lb, (float*)d_out);
}

// Round 3
// 862.102 us; speedup vs baseline: 6.7600x; 1.1738x over previous
//
#include <hip/hip_runtime.h>

#define N_NODES 100000
#define N_EDGES 1600000
#define NFEAT 256
#define NHID 128
#define NCLS 10

__device__ __forceinline__ float bf_lo(uint u) { return __uint_as_float(u << 16); }
__device__ __forceinline__ float bf_hi(uint u) { return __uint_as_float(u & 0xffff0000u); }
__device__ __forceinline__ ushort f2bf(float f) {
  uint b = __float_as_uint(f);
  return (ushort)((b + 0x7fffu + ((b >> 16) & 1u)) >> 16);   // RNE
}
__device__ __forceinline__ float b2f(ushort u) { return __uint_as_float((uint)u << 16); }

// ---------------- dense GEMM: out[n][j] = sum_k act(in[n][k]) * W[k][j] ----
// act(v) = relu(v + bias[k]) when bias != nullptr. Output packed bf16.
// BFIN: input rows are bf16 (ushort), else fp32.
template<int K, bool BFIN>
__global__ void gemm_act(const void* __restrict__ in_, const float* __restrict__ W,
                         const float* __restrict__ bias, ushort* __restrict__ out,
                         int n_nodes) {
  int tid = blockIdx.x * 256 + threadIdx.x;
  int j0 = (threadIdx.x & 31) * 4;
  int n0 = (tid >> 5) * 4;
  if (n0 >= n_nodes) return;

  float4 acc0 = {0,0,0,0}, acc1 = {0,0,0,0}, acc2 = {0,0,0,0}, acc3 = {0,0,0,0};

  for (int k0 = 0; k0 < K; k0 += 4) {
    float4 xa0, xa1, xa2, xa3;
    if constexpr (BFIN) {
      const ushort* in = (const ushort*)in_;
      ushort4 t0 = *(const ushort4*)&in[(long long)(n0+0)*K + k0];
      ushort4 t1 = *(const ushort4*)&in[(long long)(n0+1)*K + k0];
      ushort4 t2 = *(const ushort4*)&in[(long long)(n0+2)*K + k0];
      ushort4 t3 = *(const ushort4*)&in[(long long)(n0+3)*K + k0];
      xa0 = make_float4(b2f(t0.x), b2f(t0.y), b2f(t0.z), b2f(t0.w));
      xa1 = make_float4(b2f(t1.x), b2f(t1.y), b2f(t1.z), b2f(t1.w));
      xa2 = make_float4(b2f(t2.x), b2f(t2.y), b2f(t2.z), b2f(t2.w));
      xa3 = make_float4(b2f(t3.x), b2f(t3.y), b2f(t3.z), b2f(t3.w));
    } else {
      const float* in = (const float*)in_;
      xa0 = *(const float4*)&in[(long long)(n0+0)*K + k0];
      xa1 = *(const float4*)&in[(long long)(n0+1)*K + k0];
      xa2 = *(const float4*)&in[(long long)(n0+2)*K + k0];
      xa3 = *(const float4*)&in[(long long)(n0+3)*K + k0];
    }
    if (bias) {
      float4 b4 = *(const float4*)&bias[k0];
      xa0.x = fmaxf(xa0.x + b4.x, 0.f); xa0.y = fmaxf(xa0.y + b4.y, 0.f);
      xa0.z = fmaxf(xa0.z + b4.z, 0.f); xa0.w = fmaxf(xa0.w + b4.w, 0.f);
      xa1.x = fmaxf(xa1.x + b4.x, 0.f); xa1.y = fmaxf(xa1.y + b4.y, 0.f);
      xa1.z = fmaxf(xa1.z + b4.z, 0.f); xa1.w = fmaxf(xa1.w + b4.w, 0.f);
      xa2.x = fmaxf(xa2.x + b4.x, 0.f); xa2.y = fmaxf(xa2.y + b4.y, 0.f);
      xa2.z = fmaxf(xa2.z + b4.z, 0.f); xa2.w = fmaxf(xa2.w + b4.w, 0.f);
      xa3.x = fmaxf(xa3.x + b4.x, 0.f); xa3.y = fmaxf(xa3.y + b4.y, 0.f);
      xa3.z = fmaxf(xa3.z + b4.z, 0.f); xa3.w = fmaxf(xa3.w + b4.w, 0.f);
    }
    float4 w0 = *(const float4*)&W[(k0+0)*NHID + j0];
    float4 w1 = *(const float4*)&W[(k0+1)*NHID + j0];
    float4 w2 = *(const float4*)&W[(k0+2)*NHID + j0];
    float4 w3 = *(const float4*)&W[(k0+3)*NHID + j0];

#define FMA4(ACC, XA) \
    ACC.x += XA.x*w0.x + XA.y*w1.x + XA.z*w2.x + XA.w*w3.x; \
    ACC.y += XA.x*w0.y + XA.y*w1.y + XA.z*w2.y + XA.w*w3.y; \
    ACC.z += XA.x*w0.z + XA.y*w1.z + XA.z*w2.z + XA.w*w3.z; \
    ACC.w += XA.x*w0.w + XA.y*w1.w + XA.z*w2.w + XA.w*w3.w;
    FMA4(acc0, xa0) FMA4(acc1, xa1) FMA4(acc2, xa2) FMA4(acc3, xa3)
#undef FMA4
  }
#define PACK(ACC) make_ushort4(f2bf(ACC.x), f2bf(ACC.y), f2bf(ACC.z), f2bf(ACC.w))
  *(ushort4*)&out[(long long)(n0+0)*NHID + j0] = PACK(acc0);
  *(ushort4*)&out[(long long)(n0+1)*NHID + j0] = PACK(acc1);
  *(ushort4*)&out[(long long)(n0+2)*NHID + j0] = PACK(acc2);
  *(ushort4*)&out[(long long)(n0+3)*NHID + j0] = PACK(acc3);
#undef PACK
}

// ---------------- CSR build ----------------
__global__ void edge_prep(const int* __restrict__ src, const int* __restrict__ dst,
                          const float* __restrict__ ew, int* __restrict__ deg,
                          float* __restrict__ c) {
  int e = blockIdx.x * 256 + threadIdx.x;
  if (e >= N_EDGES) return;
  atomicAdd(&deg[dst[e]], 1);
  atomicAdd(&c[src[e]], ew[e]);
}

__global__ void scan1(const int* __restrict__ deg, int* __restrict__ ex,
                      int* __restrict__ bsum) {
  __shared__ int tmp[512];
  int i = blockIdx.x * 512 + threadIdx.x;
  int v = (i < N_NODES) ? deg[i] : 0;
  tmp[threadIdx.x] = v;
  __syncthreads();
  for (int off = 1; off < 512; off <<= 1) {
    int t = (threadIdx.x >= (unsigned)off) ? tmp[threadIdx.x - off] : 0;
    __syncthreads();
    tmp[threadIdx.x] += t;
    __syncthreads();
  }
  if (i < N_NODES) ex[i] = tmp[threadIdx.x] - v;
  if (threadIdx.x == 511) bsum[blockIdx.x] = tmp[511];
}

__global__ void scan2(int* __restrict__ bsum, int nb) {
  __shared__ int tmp[256];
  int v = (threadIdx.x < nb) ? bsum[threadIdx.x] : 0;
  tmp[threadIdx.x] = v;
  __syncthreads();
  for (int off = 1; off < 256; off <<= 1) {
    int t = (threadIdx.x >= (unsigned)off) ? tmp[threadIdx.x - off] : 0;
    __syncthreads();
    tmp[threadIdx.x] += t;
    __syncthreads();
  }
  if (threadIdx.x < nb) bsum[threadIdx.x] = tmp[threadIdx.x] - v;
}

__global__ void scan3(int* __restrict__ rowptr, const int* __restrict__ bsum,
                      int* __restrict__ cursor) {
  int i = blockIdx.x * 512 + threadIdx.x;
  if (i < N_NODES) {
    int r = rowptr[i] + bsum[blockIdx.x];
    rowptr[i] = r;
    cursor[i] = r;
  }
  if (i == 0) rowptr[N_NODES] = N_EDGES;
}

__global__ void fill_csr(const int* __restrict__ src, const int* __restrict__ dst,
                         const float* __restrict__ ew, int* __restrict__ cursor,
                         int2* __restrict__ sorted) {
  int e = blockIdx.x * 256 + threadIdx.x;
  if (e >= N_EDGES) return;
  int d = dst[e];
  int pos = atomicAdd(&cursor[d], 1);
  sorted[pos] = make_int2(src[e], __float_as_int(ew[e]));
}

// ---------------- gather-only aggregation (bf16 rows, 256 B/edge) ----------
// supb: bf16 rows viewed as uint (64 uints/row, uint j = features 2j,2j+1)
__global__ void aggregate(const uint* __restrict__ supb, const int* __restrict__ rowptr,
                          const int2* __restrict__ sw, uint* __restrict__ agg) {
  int node = blockIdx.x * 4 + (threadIdx.x >> 6);
  if (node >= N_NODES) return;
  int lane = threadIdx.x & 63;
  int beg = rowptr[node], end = rowptr[node + 1];
  float ax = 0.f, ay = 0.f;
  int i = beg;
  for (; i + 4 <= end; i += 4) {
    int2 m0 = sw[i], m1 = sw[i+1], m2 = sw[i+2], m3 = sw[i+3];
    uint u0 = supb[m0.x * 64 + lane];
    uint u1 = supb[m1.x * 64 + lane];
    uint u2 = supb[m2.x * 64 + lane];
    uint u3 = supb[m3.x * 64 + lane];
    float w0 = __int_as_float(m0.y), w1 = __int_as_float(m1.y);
    float w2 = __int_as_float(m2.y), w3 = __int_as_float(m3.y);
    ax += bf_lo(u0)*w0 + bf_lo(u1)*w1 + bf_lo(u2)*w2 + bf_lo(u3)*w3;
    ay += bf_hi(u0)*w0 + bf_hi(u1)*w1 + bf_hi(u2)*w2 + bf_hi(u3)*w3;
  }
  for (; i < end; i++) {
    int2 m = sw[i];
    uint u = supb[m.x * 64 + lane];
    float w = __int_as_float(m.y);
    ax += bf_lo(u) * w;
    ay += bf_hi(u) * w;
  }
  agg[node * 64 + lane] = (uint)f2bf(ax) | ((uint)f2bf(ay) << 16);
}

// layer-2 aggregate fused with weighted colsum (agg2 never materialized):
// s2[j] += sum_n c[n] * relu(agg2[n][j] + b2[j])
__global__ void aggregate_colsum(const uint* __restrict__ supb, const int* __restrict__ rowptr,
                                 const int2* __restrict__ sw, const float* __restrict__ b2,
                                 const float* __restrict__ c, float* __restrict__ s2) {
  int grp = threadIdx.x >> 6;
  int lane = threadIdx.x & 63;
  float bx = b2[lane * 2], by = b2[lane * 2 + 1];
  float csx = 0.f, csy = 0.f;
  for (int node = blockIdx.x * 4 + grp; node < N_NODES; node += gridDim.x * 4) {
    int beg = rowptr[node], end = rowptr[node + 1];
    float ax = 0.f, ay = 0.f;
    int i = beg;
    for (; i + 4 <= end; i += 4) {
      int2 m0 = sw[i], m1 = sw[i+1], m2 = sw[i+2], m3 = sw[i+3];
      uint u0 = supb[m0.x * 64 + lane];
      uint u1 = supb[m1.x * 64 + lane];
      uint u2 = supb[m2.x * 64 + lane];
      uint u3 = supb[m3.x * 64 + lane];
      float w0 = __int_as_float(m0.y), w1 = __int_as_float(m1.y);
      float w2 = __int_as_float(m2.y), w3 = __int_as_float(m3.y);
      ax += bf_lo(u0)*w0 + bf_lo(u1)*w1 + bf_lo(u2)*w2 + bf_lo(u3)*w3;
      ay += bf_hi(u0)*w0 + bf_hi(u1)*w1 + bf_hi(u2)*w2 + bf_hi(u3)*w3;
    }
    for (; i < end; i++) {
      int2 m = sw[i];
      uint u = supb[m.x * 64 + lane];
      float w = __int_as_float(m.y);
      ax += bf_lo(u) * w;
      ay += bf_hi(u) * w;
    }
    float cn = c[node];
    csx += fmaxf(ax + bx, 0.f) * cn;
    csy += fmaxf(ay + by, 0.f) * cn;
  }
  __shared__ float red[4][128];
  red[grp][lane * 2] = csx;
  red[grp][lane * 2 + 1] = csy;
  __syncthreads();
  if (grp == 0) {
    float s0 = red[0][lane*2] + red[1][lane*2] + red[2][lane*2] + red[3][lane*2];
    float s1 = red[0][lane*2+1] + red[1][lane*2+1] + red[2][lane*2+1] + red[3][lane*2+1];
    atomicAdd(&s2[lane * 2], s0);
    atomicAdd(&s2[lane * 2 + 1], s1);
  }
}

// ---------------- head: g = (s2/N) @ W3 + b3 ; out = g @ lin_w + lin_b ----
__global__ void head(const float* __restrict__ s2, const float* __restrict__ W3,
                     const float* __restrict__ b3, const float* __restrict__ lw,
                     const float* __restrict__ lb, float* __restrict__ out) {
  __shared__ float s2s[128], g[128];
  int j = threadIdx.x;
  s2s[j] = s2[j] * (1.0f / N_NODES);
  __syncthreads();
  float acc = b3[j];
  for (int k = 0; k < 128; k++) acc += s2s[k] * W3[k * NHID + j];
  g[j] = acc;
  __syncthreads();
  if (j < NCLS) {
    float o = lb[j];
    for (int k = 0; k < 128; k++) o += g[k] * lw[k * NCLS + j];
    out[j] = o;
  }
}

extern "C" void kernel_launch(void* const* d_in, const int* in_sizes, int n_in,
                              void* d_out, int out_size, void* d_ws, size_t ws_size,
                              hipStream_t stream) {
  const float* x  = (const float*)d_in[0];
  const int*   ei = (const int*)d_in[1];
  const float* ew = (const float*)d_in[2];
  const float* W1 = (const float*)d_in[3];
  const float* b1 = (const float*)d_in[4];
  const float* W2 = (const float*)d_in[5];
  const float* b2 = (const float*)d_in[6];
  const float* W3 = (const float*)d_in[7];
  const float* b3 = (const float*)d_in[8];
  const float* lw = (const float*)d_in[9];
  const float* lb = (const float*)d_in[10];
  const int* src = ei;
  const int* dst = ei + N_EDGES;

  char* ws = (char*)d_ws;
  const size_t SUP_BYTES = (size_t)N_NODES * NHID * sizeof(ushort);  // 25.6 MB (bf16)
  const size_t NODE_I    = ((size_t)(N_NODES + 1) * 4 + 511) & ~511ull;
  size_t off = 0;
  ushort* sup    = (ushort*)(ws + off); off += SUP_BYTES;
  ushort* agg    = (ushort*)(ws + off); off += SUP_BYTES;
  int*    deg    = (int*)   (ws + off); off += NODE_I;
  int*    rowptr = (int*)   (ws + off); off += NODE_I;
  int*    cursor = (int*)   (ws + off); off += NODE_I;
  float*  c      = (float*) (ws + off); off += NODE_I;
  float*  s2     = (float*) (ws + off); off += 512;
  int*    bsum   = (int*)   (ws + off); off += 1024;
  int2*   sorted = (int2*)  (ws + off); off += (size_t)N_EDGES * 8;  // 12.8 MB

  const int NB = (N_NODES + 511) / 512;

  hipMemsetAsync(deg, 0, N_NODES * sizeof(int), stream);
  hipMemsetAsync(c, 0, N_NODES * sizeof(float), stream);
  hipMemsetAsync(s2, 0, 512, stream);

  // ---- CSR build ----
  edge_prep<<<(N_EDGES + 255) / 256, 256, 0, stream>>>(src, dst, ew, deg, c);
  scan1<<<NB, 512, 0, stream>>>(deg, rowptr, bsum);
  scan2<<<1, 256, 0, stream>>>(bsum, NB);
  scan3<<<NB, 512, 0, stream>>>(rowptr, bsum, cursor);
  fill_csr<<<(N_EDGES + 255) / 256, 256, 0, stream>>>(src, dst, ew, cursor, sorted);

  // ---- layer 1 ----
  gemm_act<NFEAT, false><<<3125, 256, 0, stream>>>(x, W1, nullptr, sup, N_NODES);
  aggregate<<<25000, 256, 0, stream>>>((const uint*)sup, rowptr, sorted, (uint*)agg);

  // ---- layer 2 (+ fused layer-3 reduction) ----
  gemm_act<NHID, true><<<3125, 256, 0, stream>>>(agg, W2, b1, sup, N_NODES);
  aggregate_colsum<<<3125, 256, 0, stream>>>((const uint*)sup, rowptr, sorted, b2, c, s2);

  // ---- head ----
  head<<<1, 128, 0, stream>>>(s2, W3, b3, lw, lb, (float*)d_out);
}

// Round 4
// 618.315 us; speedup vs baseline: 9.4253x; 1.3943x over previous
//
#include <hip/hip_runtime.h>

#define N_NODES 100000
#define N_EDGES 1600000
#define NFEAT 256
#define NHID 128
#define NCLS 10

typedef __attribute__((ext_vector_type(8))) short bf16x8;
typedef __attribute__((ext_vector_type(4))) float f32x4;

__device__ __forceinline__ float bf_lo(uint u) { return __uint_as_float(u << 16); }
__device__ __forceinline__ float bf_hi(uint u) { return __uint_as_float(u & 0xffff0000u); }
__device__ __forceinline__ ushort f2bf(float f) {
  uint b = __float_as_uint(f);
  return (ushort)((b + 0x7fffu + ((b >> 16) & 1u)) >> 16);   // RNE
}
__device__ __forceinline__ uint cvt_pk_bf16(float lo, float hi) {
  uint r;
  asm("v_cvt_pk_bf16_f32 %0, %1, %2" : "=v"(r) : "v"(lo), "v"(hi));
  return r;
}

// ---------------- MFMA GEMM: out[n][j] = sum_k in[n][k] * W[k][j] ----------
// in: [n_nodes][K] fp32 (FP32IN) or bf16; W: [K][128] fp32 (converted to bf16);
// out: [n_nodes][128] bf16. Block: 4 waves, 128 rows x 128 cols.
template<int K, bool FP32IN>
__global__ __launch_bounds__(256) void gemm_mfma(const void* __restrict__ in_,
                                                 const float* __restrict__ W,
                                                 ushort* __restrict__ out, int n_nodes) {
  constexpr int PK = K + 8;                 // +8 bf16 pad = 4-bank rotation per row
  __shared__ ushort Wl[128 * PK];
  int tid = threadIdx.x;
  for (int i = tid; i < K * 128; i += 256) {   // Wl[n][k] = bf16(W[k][n])
    int k = i >> 7, n = i & 127;
    Wl[n * PK + k] = f2bf(W[i]);
  }
  __syncthreads();

  int wave = tid >> 6, lane = tid & 63;
  int lr = lane & 15, lg = lane >> 4;       // tile-row / k-group
  int rowb = blockIdx.x * 128 + wave * 32;

  f32x4 acc[2][8] = {};
  for (int k0 = 0; k0 < K; k0 += 32) {
    bf16x8 a[2];
#pragma unroll
    for (int s = 0; s < 2; s++) {
      int r = rowb + s * 16 + lr;
      r = r < n_nodes ? r : n_nodes - 1;
      if constexpr (FP32IN) {
        const float* in = (const float*)in_;
        const float* p = &in[(long long)r * K + k0 + lg * 8];
        float4 f0 = *(const float4*)p;
        float4 f1 = *(const float4*)(p + 4);
        uint4 u;
        u.x = cvt_pk_bf16(f0.x, f0.y);
        u.y = cvt_pk_bf16(f0.z, f0.w);
        u.z = cvt_pk_bf16(f1.x, f1.y);
        u.w = cvt_pk_bf16(f1.z, f1.w);
        a[s] = *(bf16x8*)&u;
      } else {
        const ushort* in = (const ushort*)in_;
        a[s] = *(const bf16x8*)&in[(long long)r * K + k0 + lg * 8];
      }
    }
#pragma unroll
    for (int nt = 0; nt < 8; nt++) {
      bf16x8 b = *(const bf16x8*)&Wl[(nt * 16 + lr) * PK + k0 + lg * 8];
      acc[0][nt] = __builtin_amdgcn_mfma_f32_16x16x32_bf16(a[0], b, acc[0][nt], 0, 0, 0);
      acc[1][nt] = __builtin_amdgcn_mfma_f32_16x16x32_bf16(a[1], b, acc[1][nt], 0, 0, 0);
    }
  }
  // C/D: col = lane&15 (within n-tile), row = (lane>>4)*4 + reg  [m89 mapping]
#pragma unroll
  for (int s = 0; s < 2; s++)
#pragma unroll
    for (int reg = 0; reg < 4; reg++) {
      int r = rowb + s * 16 + lg * 4 + reg;
      if (r < n_nodes) {
#pragma unroll
        for (int nt = 0; nt < 8; nt++)
          out[(long long)r * 128 + nt * 16 + lr] = f2bf(acc[s][nt][reg]);
      }
    }
}

// ---------------- CSR build ----------------
__global__ void edge_prep(const int* __restrict__ src, const int* __restrict__ dst,
                          const float* __restrict__ ew, int* __restrict__ deg,
                          float* __restrict__ c) {
  int e = blockIdx.x * 256 + threadIdx.x;
  if (e >= N_EDGES) return;
  atomicAdd(&deg[dst[e]], 1);
  atomicAdd(&c[src[e]], ew[e]);
}

__global__ void scan1(const int* __restrict__ deg, int* __restrict__ ex,
                      int* __restrict__ bsum) {
  __shared__ int tmp[512];
  int i = blockIdx.x * 512 + threadIdx.x;
  int v = (i < N_NODES) ? deg[i] : 0;
  tmp[threadIdx.x] = v;
  __syncthreads();
  for (int off = 1; off < 512; off <<= 1) {
    int t = (threadIdx.x >= (unsigned)off) ? tmp[threadIdx.x - off] : 0;
    __syncthreads();
    tmp[threadIdx.x] += t;
    __syncthreads();
  }
  if (i < N_NODES) ex[i] = tmp[threadIdx.x] - v;
  if (threadIdx.x == 511) bsum[blockIdx.x] = tmp[511];
}

__global__ void scan2(int* __restrict__ bsum, int nb) {
  __shared__ int tmp[256];
  int v = (threadIdx.x < nb) ? bsum[threadIdx.x] : 0;
  tmp[threadIdx.x] = v;
  __syncthreads();
  for (int off = 1; off < 256; off <<= 1) {
    int t = (threadIdx.x >= (unsigned)off) ? tmp[threadIdx.x - off] : 0;
    __syncthreads();
    tmp[threadIdx.x] += t;
    __syncthreads();
  }
  if (threadIdx.x < nb) bsum[threadIdx.x] = tmp[threadIdx.x] - v;
}

__global__ void scan3(int* __restrict__ rowptr, const int* __restrict__ bsum,
                      int* __restrict__ cursor) {
  int i = blockIdx.x * 512 + threadIdx.x;
  if (i < N_NODES) {
    int r = rowptr[i] + bsum[blockIdx.x];
    rowptr[i] = r;
    cursor[i] = r;
  }
  if (i == 0) rowptr[N_NODES] = N_EDGES;
}

__global__ void fill_csr(const int* __restrict__ src, const int* __restrict__ dst,
                         const float* __restrict__ ew, int* __restrict__ cursor,
                         int2* __restrict__ sorted) {
  int e = blockIdx.x * 256 + threadIdx.x;
  if (e >= N_EDGES) return;
  int d = dst[e];
  int pos = atomicAdd(&cursor[d], 1);
  sorted[pos] = make_int2(src[e], __float_as_int(ew[e]));
}

// ---------------- gather aggregation (bf16 rows, 256 B/edge) ---------------
// agg[n][:] = relu(bias + sum_{e in bucket(n)} sup[src_e][:] * w_e)
__global__ void aggregate(const uint* __restrict__ supb, const int* __restrict__ rowptr,
                          const int2* __restrict__ sw, const float* __restrict__ bias,
                          uint* __restrict__ agg) {
  int node = blockIdx.x * 4 + (threadIdx.x >> 6);
  if (node >= N_NODES) return;
  int lane = threadIdx.x & 63;
  int beg = rowptr[node], end = rowptr[node + 1];
  float ax = 0.f, ay = 0.f;
  int i = beg;
  for (; i + 4 <= end; i += 4) {
    int2 m0 = sw[i], m1 = sw[i+1], m2 = sw[i+2], m3 = sw[i+3];
    uint u0 = supb[m0.x * 64 + lane];
    uint u1 = supb[m1.x * 64 + lane];
    uint u2 = supb[m2.x * 64 + lane];
    uint u3 = supb[m3.x * 64 + lane];
    float w0 = __int_as_float(m0.y), w1 = __int_as_float(m1.y);
    float w2 = __int_as_float(m2.y), w3 = __int_as_float(m3.y);
    ax += bf_lo(u0)*w0 + bf_lo(u1)*w1 + bf_lo(u2)*w2 + bf_lo(u3)*w3;
    ay += bf_hi(u0)*w0 + bf_hi(u1)*w1 + bf_hi(u2)*w2 + bf_hi(u3)*w3;
  }
  for (; i < end; i++) {
    int2 m = sw[i];
    uint u = supb[m.x * 64 + lane];
    float w = __int_as_float(m.y);
    ax += bf_lo(u) * w;
    ay += bf_hi(u) * w;
  }
  ax = fmaxf(ax + bias[lane * 2], 0.f);
  ay = fmaxf(ay + bias[lane * 2 + 1], 0.f);
  agg[node * 64 + lane] = (uint)f2bf(ax) | ((uint)f2bf(ay) << 16);
}

// layer-2 aggregate fused with weighted colsum (agg2 never materialized):
// s2[j] += sum_n c[n] * relu(agg2[n][j] + b2[j])
__global__ void aggregate_colsum(const uint* __restrict__ supb, const int* __restrict__ rowptr,
                                 const int2* __restrict__ sw, const float* __restrict__ b2,
                                 const float* __restrict__ c, float* __restrict__ s2) {
  int grp = threadIdx.x >> 6;
  int lane = threadIdx.x & 63;
  float bx = b2[lane * 2], by = b2[lane * 2 + 1];
  float csx = 0.f, csy = 0.f;
  for (int node = blockIdx.x * 4 + grp; node < N_NODES; node += gridDim.x * 4) {
    int beg = rowptr[node], end = rowptr[node + 1];
    float ax = 0.f, ay = 0.f;
    int i = beg;
    for (; i + 4 <= end; i += 4) {
      int2 m0 = sw[i], m1 = sw[i+1], m2 = sw[i+2], m3 = sw[i+3];
      uint u0 = supb[m0.x * 64 + lane];
      uint u1 = supb[m1.x * 64 + lane];
      uint u2 = supb[m2.x * 64 + lane];
      uint u3 = supb[m3.x * 64 + lane];
      float w0 = __int_as_float(m0.y), w1 = __int_as_float(m1.y);
      float w2 = __int_as_float(m2.y), w3 = __int_as_float(m3.y);
      ax += bf_lo(u0)*w0 + bf_lo(u1)*w1 + bf_lo(u2)*w2 + bf_lo(u3)*w3;
      ay += bf_hi(u0)*w0 + bf_hi(u1)*w1 + bf_hi(u2)*w2 + bf_hi(u3)*w3;
    }
    for (; i < end; i++) {
      int2 m = sw[i];
      uint u = supb[m.x * 64 + lane];
      float w = __int_as_float(m.y);
      ax += bf_lo(u) * w;
      ay += bf_hi(u) * w;
    }
    float cn = c[node];
    csx += fmaxf(ax + bx, 0.f) * cn;
    csy += fmaxf(ay + by, 0.f) * cn;
  }
  __shared__ float red[4][128];
  red[grp][lane * 2] = csx;
  red[grp][lane * 2 + 1] = csy;
  __syncthreads();
  if (grp == 0) {
    float s0 = red[0][lane*2] + red[1][lane*2] + red[2][lane*2] + red[3][lane*2];
    float s1 = red[0][lane*2+1] + red[1][lane*2+1] + red[2][lane*2+1] + red[3][lane*2+1];
    atomicAdd(&s2[lane * 2], s0);
    atomicAdd(&s2[lane * 2 + 1], s1);
  }
}

// ---------------- head: g = (s2/N) @ W3 + b3 ; out = g @ lin_w + lin_b ----
__global__ void head(const float* __restrict__ s2, const float* __restrict__ W3,
                     const float* __restrict__ b3, const float* __restrict__ lw,
                     const float* __restrict__ lb, float* __restrict__ out) {
  __shared__ float s2s[128], g[128];
  int j = threadIdx.x;
  s2s[j] = s2[j] * (1.0f / N_NODES);
  __syncthreads();
  float acc = b3[j];
  for (int k = 0; k < 128; k++) acc += s2s[k] * W3[k * NHID + j];
  g[j] = acc;
  __syncthreads();
  if (j < NCLS) {
    float o = lb[j];
    for (int k = 0; k < 128; k++) o += g[k] * lw[k * NCLS + j];
    out[j] = o;
  }
}

extern "C" void kernel_launch(void* const* d_in, const int* in_sizes, int n_in,
                              void* d_out, int out_size, void* d_ws, size_t ws_size,
                              hipStream_t stream) {
  const float* x  = (const float*)d_in[0];
  const int*   ei = (const int*)d_in[1];
  const float* ew = (const float*)d_in[2];
  const float* W1 = (const float*)d_in[3];
  const float* b1 = (const float*)d_in[4];
  const float* W2 = (const float*)d_in[5];
  const float* b2 = (const float*)d_in[6];
  const float* W3 = (const float*)d_in[7];
  const float* b3 = (const float*)d_in[8];
  const float* lw = (const float*)d_in[9];
  const float* lb = (const float*)d_in[10];
  const int* src = ei;
  const int* dst = ei + N_EDGES;

  char* ws = (char*)d_ws;
  const size_t SUP_BYTES = (size_t)N_NODES * NHID * sizeof(ushort);  // 25.6 MB (bf16)
  const size_t NODE_I    = ((size_t)(N_NODES + 1) * 4 + 511) & ~511ull;
  size_t off = 0;
  ushort* sup    = (ushort*)(ws + off); off += SUP_BYTES;
  ushort* agg    = (ushort*)(ws + off); off += SUP_BYTES;
  int*    deg    = (int*)   (ws + off); off += NODE_I;
  int*    rowptr = (int*)   (ws + off); off += NODE_I;
  int*    cursor = (int*)   (ws + off); off += NODE_I;
  float*  c      = (float*) (ws + off); off += NODE_I;
  float*  s2     = (float*) (ws + off); off += 512;
  int*    bsum   = (int*)   (ws + off); off += 1024;
  int2*   sorted = (int2*)  (ws + off); off += (size_t)N_EDGES * 8;  // 12.8 MB

  const int NB = (N_NODES + 511) / 512;
  const int GB = (N_NODES + 127) / 128;   // 782 gemm blocks

  hipMemsetAsync(deg, 0, N_NODES * sizeof(int), stream);
  hipMemsetAsync(c, 0, N_NODES * sizeof(float), stream);
  hipMemsetAsync(s2, 0, 512, stream);

  // ---- CSR build ----
  edge_prep<<<(N_EDGES + 255) / 256, 256, 0, stream>>>(src, dst, ew, deg, c);
  scan1<<<NB, 512, 0, stream>>>(deg, rowptr, bsum);
  scan2<<<1, 256, 0, stream>>>(bsum, NB);
  scan3<<<NB, 512, 0, stream>>>(rowptr, bsum, cursor);
  fill_csr<<<(N_EDGES + 255) / 256, 256, 0, stream>>>(src, dst, ew, cursor, sorted);

  // ---- layer 1: sup = bf16(x @ W1) ; agg = relu(A @ sup + b1) ----
  gemm_mfma<NFEAT, true><<<GB, 256, 0, stream>>>(x, W1, sup, N_NODES);
  aggregate<<<25000, 256, 0, stream>>>((const uint*)sup, rowptr, sorted, b1, (uint*)agg);

  // ---- layer 2: sup = bf16(agg @ W2) ; s2 = c^T relu(A sup + b2) ----
  gemm_mfma<NHID, false><<<GB, 256, 0, stream>>>(agg, W2, sup, N_NODES);
  aggregate_colsum<<<3125, 256, 0, stream>>>((const uint*)sup, rowptr, sorted, b2, c, s2);

  // ---- head ----
  head<<<1, 128, 0, stream>>>(s2, W3, b3, lw, lb, (float*)d_out);
}